// Round 3
// baseline (77.794 us; speedup 1.0000x reference)
//
#include <hip/hip_runtime.h>
#include <math.h>

#define BLOCK 256
#define SPLIT 4            // threads cooperating on one pixel (each does kv/SPLIT edges)
#define MAX_KV_LDS 1024    // 8 KiB LDS cap for the staged-contour path

// tanh(1e5*cross) = 1 - 2/(exp(2e5*cross)+1); branchless, exact saturation.
__device__ __forceinline__ float fast_tanh_k(float cross)
{
    float e = __expf(cross * 200000.0f);
    return fmaf(-2.0f, __builtin_amdgcn_rcpf(e + 1.0f), 1.0f);
}

// Abramowitz-Stegun 4.4.45: acos(x) ~ sqrt(1-x)*poly(x), max err 6.7e-5 rad.
__device__ __forceinline__ float fast_acos(float x)
{
    float y = fabsf(x);
    float p = fmaf(-0.0187293f, y, 0.0742610f);
    p = fmaf(p, y, -0.2121144f);
    p = fmaf(p, y, 1.5707288f);
    float a = sqrtf(1.0f - y) * p;
    return (x >= 0.0f) ? a : (3.14159265358979f - a);
}

// Winding-angle partial sum over edges [k0, k1) for one pixel.
template <typename VP>
__device__ __forceinline__ float winding_partial(VP vsrc, int kv, int k0, int k1,
                                                 float mx, float my)
{
    float acc = 0.0f;
    if (k0 >= k1) return acc;
    float2 v = vsrc[k0];
    float dx = v.x - mx, dy = v.y - my;
    float nd2 = fmaf(dx, dx, dy * dy);       // ||diff||^2 carried forward

    #pragma unroll 4
    for (int k = k0; k < k1; ++k) {
        int kn = k + 1;
        if (kn == kv) kn = 0;                // wraparound vertex
        float2 vn = vsrc[kn];
        float rx = vn.x - mx, ry = vn.y - my;
        float cross = dy * rx - dx * ry;     // matches reference sign
        float dot   = fmaf(dx, rx, dy * ry);
        float nr2   = fmaf(rx, rx, ry * ry);
        float cosang = dot * __builtin_amdgcn_rsqf(nd2 * nr2);
        cosang = __builtin_amdgcn_fmed3f(cosang, -1.0f + 1e-5f, 1.0f - 1e-5f);
        acc = fmaf(fast_tanh_k(cross), fast_acos(cosang), acc);
        dx = rx; dy = ry; nd2 = nr2;
    }
    return acc;
}

__global__ __launch_bounds__(BLOCK)
void contour_mask_kernel(const float2* __restrict__ contour,
                         const int* __restrict__ size_ptr,
                         float* __restrict__ out,
                         int out_size, int in0_elems)
{
    __shared__ float2 verts[MAX_KV_LDS];

    const int size     = *size_ptr;          // scalar (wave-uniform) load
    const int S2       = size * size;
    const int bn_total = out_size / S2;
    const int kv       = in0_elems / (bn_total * 2);

    const int tid   = threadIdx.x;
    const int idx4  = blockIdx.x * BLOCK + tid;
    const int pixel = idx4 >> 2;             // SPLIT=4 threads per pixel
    const int seg   = tid & (SPLIT - 1);

    // first/last pixel this block touches (for single-bn LDS staging)
    const int p_first = (blockIdx.x * BLOCK) >> 2;
    const int p_last  = ((blockIdx.x + 1) * BLOCK - 1) >> 2;
    const int bn0     = p_first / S2;
    const bool use_lds = (kv <= MAX_KV_LDS) && (bn0 == p_last / S2);

    if (use_lds) {
        for (int i = tid; i < kv; i += BLOCK)
            verts[i] = contour[(size_t)bn0 * kv + i];
    }
    __syncthreads();

    float acc = 0.0f;
    if (pixel < out_size) {
        const int bn = pixel / S2;
        const int p  = pixel - bn * S2;
        const float inv_size = 1.0f / (float)size;
        const int pi = p / size;
        const int pj = p - pi * size;
        // mesh = meshgrid(g,g,'ij').reshape(-1,2)/size: ch0 = i/size, ch1 = j/size
        const float mx = (float)pi * inv_size;
        const float my = (float)pj * inv_size;

        const int q  = (kv + SPLIT - 1) / SPLIT;   // edges per segment
        const int k0 = seg * q;
        const int k1 = min(k0 + q, kv);

        if (use_lds)
            acc = winding_partial(verts, kv, k0, k1, mx, my);
        else
            acc = winding_partial(contour + (size_t)bn * kv, kv, k0, k1, mx, my);
    }

    // combine the 4 partial sums for this pixel (lanes i, i^1, i^2)
    acc += __shfl_xor(acc, 1, 64);
    acc += __shfl_xor(acc, 2, 64);

    if (pixel < out_size && seg == 0) {
        float res = fabsf(acc) * 0.15915494309189535f;   // |sum| / 2pi
        out[pixel] = fminf(res, 1.0f);
    }
}

extern "C" void kernel_launch(void* const* d_in, const int* in_sizes, int n_in,
                              void* d_out, int out_size, void* d_ws, size_t ws_size,
                              hipStream_t stream)
{
    const float2* contour  = (const float2*)d_in[0];
    const int*    size_ptr = (const int*)d_in[1];
    float*        out      = (float*)d_out;

    // SPLIT threads per output pixel
    const long long threads = (long long)out_size * SPLIT;
    const int blocks = (int)((threads + BLOCK - 1) / BLOCK);
    contour_mask_kernel<<<blocks, BLOCK, 0, stream>>>(
        contour, size_ptr, out, out_size, in_sizes[0]);
}

// Round 4
// 68.021 us; speedup vs baseline: 1.1437x; 1.1437x over previous
//
#include <hip/hip_runtime.h>
#include <math.h>

#define BLOCK 256
#define SPLIT 4            // threads cooperating per pixel-pair (each does kv/SPLIT edges)
#define PPT   2            // pixels per thread, packed into v2f lanes
#define MAX_KV_LDS 1024    // 8 KiB LDS cap for the staged-contour path

typedef float v2f __attribute__((ext_vector_type(2)));

// raw single-instruction trans ops (~1 ulp; we have 2e-2 absmax slack)
__device__ __forceinline__ float rsq1(float x)  { return __builtin_amdgcn_rsqf(x); }
__device__ __forceinline__ float sqrt1(float x) { return __builtin_amdgcn_sqrtf(x); }
__device__ __forceinline__ float rcp1(float x)  { return __builtin_amdgcn_rcpf(x); }

// ---- packed 2-pixel winding partial sum over edges [k0,k1) ----
// Component i of the v2f lanes is pixel i of the pair; the vertex stream is
// shared (one ds_read per edge for both pixels).
template <typename VP>
__device__ __forceinline__ v2f winding_partial_pk(VP vsrc, int kv, int k0, int k1,
                                                  v2f mx2, v2f my2)
{
    v2f acc = {0.0f, 0.0f};
    if (k0 >= k1) return acc;
    float2 v = vsrc[k0];
    v2f dx2 = v.x - mx2;
    v2f dy2 = v.y - my2;
    v2f nd2 = dx2 * dx2 + dy2 * dy2;

    #pragma unroll 4
    for (int k = k0; k < k1; ++k) {
        int kn = k + 1;
        if (kn == kv) kn = 0;                       // wraparound vertex
        float2 vn = vsrc[kn];
        v2f rx2 = vn.x - mx2;
        v2f ry2 = vn.y - my2;
        v2f cross = dy2 * rx2 - dx2 * ry2;          // matches reference sign
        v2f dot   = dx2 * rx2 + dy2 * ry2;
        v2f nr2   = rx2 * rx2 + ry2 * ry2;
        v2f n2    = nd2 * nr2;
        v2f inv   = { rsq1(n2.x), rsq1(n2.y) };
        v2f c     = dot * inv;
        c.x = __builtin_amdgcn_fmed3f(c.x, -0.99999f, 0.99999f);
        c.y = __builtin_amdgcn_fmed3f(c.y, -0.99999f, 0.99999f);
        // fast acos (A&S 4.4.45, max err 6.7e-5 rad), reflected for c<0
        v2f y = { fabsf(c.x), fabsf(c.y) };
        v2f p = -0.0187293f * y + 0.0742610f;
        p = p * y + -0.2121144f;
        p = p * y + 1.5707288f;
        v2f s = { sqrt1(1.0f - y.x), sqrt1(1.0f - y.y) };
        v2f a = s * p;
        v2f ar = 3.14159265358979f - a;
        a.x = (c.x >= 0.0f) ? a.x : ar.x;
        a.y = (c.y >= 0.0f) ? a.y : ar.y;
        // tanh(1e5*cross) = 1 - 2/(exp(2e5*cross)+1), branchless saturation
        v2f t = cross * 200000.0f;
        v2f th;
        th.x = fmaf(-2.0f, rcp1(__expf(t.x) + 1.0f), 1.0f);
        th.y = fmaf(-2.0f, rcp1(__expf(t.y) + 1.0f), 1.0f);
        acc = acc + th * a;
        dx2 = rx2; dy2 = ry2; nd2 = nr2;
    }
    return acc;
}

// ---- scalar fallback (cold: blocks straddling an image boundary) ----
template <typename VP>
__device__ __forceinline__ float winding_partial(VP vsrc, int kv, int k0, int k1,
                                                 float mx, float my)
{
    float acc = 0.0f;
    if (k0 >= k1) return acc;
    float2 v = vsrc[k0];
    float dx = v.x - mx, dy = v.y - my;
    float nd2 = fmaf(dx, dx, dy * dy);
    for (int k = k0; k < k1; ++k) {
        int kn = k + 1;
        if (kn == kv) kn = 0;
        float2 vn = vsrc[kn];
        float rx = vn.x - mx, ry = vn.y - my;
        float cross = dy * rx - dx * ry;
        float dot   = fmaf(dx, rx, dy * ry);
        float nr2   = fmaf(rx, rx, ry * ry);
        float c = dot * rsq1(nd2 * nr2);
        c = __builtin_amdgcn_fmed3f(c, -0.99999f, 0.99999f);
        float yy = fabsf(c);
        float p = fmaf(-0.0187293f, yy, 0.0742610f);
        p = fmaf(p, yy, -0.2121144f);
        p = fmaf(p, yy, 1.5707288f);
        float a = sqrt1(1.0f - yy) * p;
        a = (c >= 0.0f) ? a : (3.14159265358979f - a);
        float th = fmaf(-2.0f, rcp1(__expf(cross * 200000.0f) + 1.0f), 1.0f);
        acc = fmaf(th, a, acc);
        dx = rx; dy = ry; nd2 = nr2;
    }
    return acc;
}

__global__ __launch_bounds__(BLOCK)
void contour_mask_kernel(const float2* __restrict__ contour,
                         const int* __restrict__ size_ptr,
                         float* __restrict__ out,
                         int out_size, int in0_elems)
{
    __shared__ float2 verts[MAX_KV_LDS];

    const int size     = *size_ptr;            // wave-uniform scalar load
    const int S2       = size * size;
    const int bn_total = out_size / S2;
    const int kv       = in0_elems / (bn_total * 2);

    const int tid  = threadIdx.x;
    const int PIX_PER_BLOCK = (BLOCK / SPLIT) * PPT;     // 128
    const int base = blockIdx.x * PIX_PER_BLOCK;

    const int bn0 = base / S2;                 // uniform (scalar) divide
    const int rem = base - bn0 * S2;
    const bool one_image = (rem + PIX_PER_BLOCK <= S2) &&
                           (base + PIX_PER_BLOCK <= out_size);
    const bool use_lds = (kv <= MAX_KV_LDS) && one_image;

    if (use_lds) {
        for (int i = tid; i < kv; i += BLOCK)
            verts[i] = contour[(size_t)bn0 * kv + i];
    }
    __syncthreads();

    const int seg = tid & (SPLIT - 1);
    const int q   = (kv + SPLIT - 1) / SPLIT;  // edges per segment
    const int k0  = min(seg * q, kv);
    const int k1  = min(k0 + q, kv);
    const float inv_size = 1.0f / (float)size;
    const float INV2PI = 0.15915494309189535f;

    if (use_lds) {
        // uniform scalar decomposition of the block's first pixel
        const int pi0 = rem / size;            // uniform
        const int pj0 = rem - pi0 * size;
        const int t   = (tid / SPLIT) * PPT;   // even local pixel offset

        int pjA = pj0 + t, piA = pi0;
        while (pjA >= size) { pjA -= size; ++piA; }   // <=2 iters for size>=64
        int pjB = pjA + 1, piB = piA;
        if (pjB >= size) { pjB = 0; ++piB; }

        // mesh: ch0 = i/size, ch1 = j/size  (meshgrid 'ij')
        v2f mx2 = { piA * inv_size, piB * inv_size };
        v2f my2 = { pjA * inv_size, pjB * inv_size };

        v2f acc = winding_partial_pk(verts, kv, k0, k1, mx2, my2);
        // combine the 4 partial sums for this pixel-pair (lanes i, i^1, i^2)
        acc.x += __shfl_xor(acc.x, 1, 64);
        acc.y += __shfl_xor(acc.y, 1, 64);
        acc.x += __shfl_xor(acc.x, 2, 64);
        acc.y += __shfl_xor(acc.y, 2, 64);

        if (seg == 0) {
            float2 res;
            res.x = fminf(fabsf(acc.x) * INV2PI, 1.0f);
            res.y = fminf(fabsf(acc.y) * INV2PI, 1.0f);
            *(float2*)(out + base + t) = res;   // 8B-aligned coalesced store
        }
    } else {
        // cold path: per-pixel scalar with generic indexing
        #pragma unroll
        for (int px = 0; px < PPT; ++px) {
            const int pixel = base + (tid / SPLIT) * PPT + px;
            float a = 0.0f;
            int bn = 0;
            if (pixel < out_size) {
                bn = pixel / S2;
                const int p  = pixel - bn * S2;
                const int pi = p / size;
                const int pj = p - pi * size;
                a = winding_partial(contour + (size_t)bn * kv, kv, k0, k1,
                                    pi * inv_size, pj * inv_size);
            }
            a += __shfl_xor(a, 1, 64);
            a += __shfl_xor(a, 2, 64);
            if (pixel < out_size && seg == 0)
                out[pixel] = fminf(fabsf(a) * INV2PI, 1.0f);
        }
    }
}

extern "C" void kernel_launch(void* const* d_in, const int* in_sizes, int n_in,
                              void* d_out, int out_size, void* d_ws, size_t ws_size,
                              hipStream_t stream)
{
    const float2* contour  = (const float2*)d_in[0];
    const int*    size_ptr = (const int*)d_in[1];
    float*        out      = (float*)d_out;

    const int PIX_PER_BLOCK = (BLOCK / SPLIT) * PPT;   // 128 pixels per block
    const int blocks = (out_size + PIX_PER_BLOCK - 1) / PIX_PER_BLOCK;
    contour_mask_kernel<<<blocks, BLOCK, 0, stream>>>(
        contour, size_ptr, out, out_size, in_sizes[0]);
}